// Round 1
// baseline (643.837 us; speedup 1.0000x reference)
//
#include <hip/hip_runtime.h>
#include <hip/hip_bf16.h>

// ---------------------------------------------------------------------------
// GraphEncoder (VGAE 2-layer GCN + reparam), fp32 in/out, edge_index int32.
// Round 9: XCD-local column-sliced gathers.
//  * xs / ts stored in 8 column-slices of 16 cols (3.2 MB each); gather
//    blocks use blockIdx%8 == slice so each XCD's L2 holds exactly one
//    slice -> edge gathers (410 MB logical) become L2 hits.
//  * gather kernels: 2 lanes/node, 16-edge chunks, 8-deep uint4 staging,
//    next-chunk csr index prefetch (nt loads), branch-free zero-row pads.
//  * layer-1 GEMM decoupled into a small dense MFMA pass y -> tsP, tsP
//    written in paired {mu8|ls8} slice layout for the fused z epilogue.
// Math: y = dd*(xs[d]+sum xs[s]) ; ts = (y@Wf + bb)*dis ; out = dd*(ts[d]+
//       sum ts[s]) + bcat ;  Wf = W1@[Wmu|Wls], bb = b1@[Wmu|Wls].
// ---------------------------------------------------------------------------

typedef unsigned int u32;
typedef unsigned short u16;
typedef unsigned char u8;
typedef __bf16 bf16x8 __attribute__((ext_vector_type(8)));
typedef float f32x4 __attribute__((ext_vector_type(4)));
typedef u32 u32x2 __attribute__((ext_vector_type(2)));
typedef u32 u32x4 __attribute__((ext_vector_type(4)));

__device__ __forceinline__ u16 f2bf(float f) {  // fp32 -> bf16 RNE
    union { float f; u32 u; } v; v.f = f;
    u32 u = v.u;
    u += 0x7fffu + ((u >> 16) & 1u);
    return (u16)(u >> 16);
}
__device__ __forceinline__ float bflo(u32 p) {
    union { u32 u; float f; } v; v.u = p << 16; return v.f;
}
__device__ __forceinline__ float bfhi(u32 p) {
    union { u32 u; float f; } v; v.u = p & 0xffff0000u; return v.f;
}

// ---------------- degree histogram + per-edge u8 local offset (x4) ----------
__global__ __launch_bounds__(256) void deg_hist(const int* __restrict__ dst,
                                                u32* __restrict__ deg,
                                                u8* __restrict__ loc, int E) {
    int i4 = (blockIdx.x * 256 + threadIdx.x) * 4;
    if (i4 + 3 < E) {
        int4 d4 = *(const int4*)(dst + i4);
        uchar4 l4;
        l4.x = (u8)atomicAdd(&deg[d4.x], 1u);
        l4.y = (u8)atomicAdd(&deg[d4.y], 1u);
        l4.z = (u8)atomicAdd(&deg[d4.z], 1u);
        l4.w = (u8)atomicAdd(&deg[d4.w], 1u);
        *(uchar4*)(loc + i4) = l4;
    } else {
        for (int i = i4; i < E; ++i) loc[i] = (u8)atomicAdd(&deg[dst[i]], 1u);
    }
}

// ---------------- scan A: per-block totals ----------------
__global__ __launch_bounds__(256) void scanA(const u32* __restrict__ deg,
                                             u32* __restrict__ blockSums, int N) {
    __shared__ u32 s[256];
    int t = threadIdx.x, i = blockIdx.x * 256 + t;
    s[t] = (i < N) ? deg[i] : 0u;
    for (int off = 128; off > 0; off >>= 1) {
        __syncthreads();
        if (t < off) s[t] += s[t + off];
    }
    if (t == 0) blockSums[blockIdx.x] = s[0];
}

// ---------------- scan B: exclusive scan of block totals (1 block) ----------
__global__ __launch_bounds__(512) void scanB(const u32* __restrict__ blockSums,
                                             u32* __restrict__ blockOffs, int NB) {
    __shared__ u32 s[512];
    int t = threadIdx.x;
    u32 v = (t < NB) ? blockSums[t] : 0u;
    s[t] = v;
    for (int off = 1; off < 512; off <<= 1) {
        __syncthreads();
        u32 add = (t >= off) ? s[t - off] : 0u;
        __syncthreads();
        s[t] += add;
    }
    __syncthreads();
    if (t < NB) blockOffs[t] = s[t] - v;  // exclusive
}

// ---------------- scan C: rowstart + dis ----------------
__global__ __launch_bounds__(256) void scanC(const u32* __restrict__ deg,
                                             const u32* __restrict__ blockOffs,
                                             u32* __restrict__ rowstart,
                                             float* __restrict__ dis, int N, int E) {
    __shared__ u32 s[256];
    int t = threadIdx.x, i = blockIdx.x * 256 + t;
    u32 v = (i < N) ? deg[i] : 0u;
    s[t] = v;
    for (int off = 1; off < 256; off <<= 1) {
        __syncthreads();
        u32 add = (t >= off) ? s[t - off] : 0u;
        __syncthreads();
        s[t] += add;
    }
    __syncthreads();
    if (i < N) {
        rowstart[i] = blockOffs[blockIdx.x] + s[t] - v;  // exclusive
        dis[i] = rsqrtf((float)v + 1.0f);
    }
    if (i == 0) rowstart[N] = (u32)E;
}

// ---------------- CSR placement (x4, pure scattered store) ------------------
__global__ __launch_bounds__(256) void place_kernel(const int* __restrict__ src,
                                                    const int* __restrict__ dst,
                                                    const u8* __restrict__ loc,
                                                    const u32* __restrict__ rowstart,
                                                    int* __restrict__ csr, int E) {
    int i4 = (blockIdx.x * 256 + threadIdx.x) * 4;
    if (i4 + 3 < E) {
        int4 s4 = *(const int4*)(src + i4);
        int4 d4 = *(const int4*)(dst + i4);
        uchar4 l4 = *(const uchar4*)(loc + i4);
        csr[rowstart[d4.x] + l4.x] = s4.x;
        csr[rowstart[d4.y] + l4.y] = s4.y;
        csr[rowstart[d4.z] + l4.z] = s4.z;
        csr[rowstart[d4.w] + l4.w] = s4.w;
    } else {
        for (int i = i4; i < E; ++i) csr[rowstart[dst[i]] + loc[i]] = src[i];
    }
}

// ---------------- fuse weights: WfT(bf16) = (W1@[Wmu|Wls])^T, bb, bcat ------
__global__ __launch_bounds__(256) void fuse_w(const float* __restrict__ W1,
                                              const float* __restrict__ Wmu,
                                              const float* __restrict__ Wls,
                                              const float* __restrict__ b1,
                                              const float* __restrict__ bmu,
                                              const float* __restrict__ bls,
                                              u16* __restrict__ WfT,
                                              float* __restrict__ bb,
                                              float* __restrict__ bcat) {
    int idx = blockIdx.x * 256 + threadIdx.x;  // 16384
    if (idx >= 16384) return;
    int k = idx >> 7, n = idx & 127;
    const float* Wcol = (n < 64) ? (Wmu + n) : (Wls + (n - 64));
    float acc = 0.f;
#pragma unroll 8
    for (int j = 0; j < 128; ++j) acc += W1[k * 128 + j] * Wcol[j * 64];
    WfT[n * 128 + k] = f2bf(acc);  // transposed, bf16
    if (k == 0) {
        float accb = 0.f;
#pragma unroll 8
        for (int j = 0; j < 128; ++j) accb += b1[j] * Wcol[j * 64];
        bb[n] = accb;
        bcat[n] = (n < 64) ? bmu[n] : bls[n - 64];
    }
}

// ---------------- xsP = bf16(x * dis[node]) in 8x16-col slice layout --------
// slice s holds cols [16s,16s+16) : u16 xsP[s][(N+1)][16] (32B/node/slice).
// Row N of every slice is zeroed (branch-free dummy reads; also serves as
// the zero row of tsP, which aliases this buffer).
__global__ __launch_bounds__(256) void convert_x(const float* __restrict__ x,
                                                 const float* __restrict__ dis,
                                                 u32* __restrict__ xsP, int N) {
    long i = (long)blockIdx.x * 256 + threadIdx.x;  // (N+1)*32 threads
    long node = i >> 5;
    int j = (int)(i & 31);
    if (node > N) return;
    int s = j >> 2, q = j & 3;
    u32x2* dst = (u32x2*)((char*)xsP + ((size_t)s * (N + 1) + node) * 32 + q * 8);
    if (node == N) {
        u32x2 z = {0u, 0u};
        __builtin_nontemporal_store(z, dst);
        return;
    }
    float dd = dis[node];
    f32x4 v = ((const f32x4*)x)[i];
    u32x2 o;
    o.x = (u32)f2bf(v[0] * dd) | ((u32)f2bf(v[1] * dd) << 16);
    o.y = (u32)f2bf(v[2] * dd) | ((u32)f2bf(v[3] * dd) << 16);
    __builtin_nontemporal_store(o, dst);
}

// ---------------- shared sliced-gather skeleton -----------------------------
// 2 lanes/node (p = parity -> which 16B chunk of the 32B slice row), 16-edge
// chunks, guarded nt csr index loads prefetched one chunk ahead, 8-deep uint4
// gather staging. Out-of-range edges read the zeroed row N.
#define GATHER_SLICE()                                                          \
    int pairbase = (tid & 63) & ~1;                                             \
    int id[8];                                                                  \
    u32 e0 = beg;                                                               \
    if (e0 < end) {                                                             \
        _Pragma("unroll")                                                       \
        for (int k = 0; k < 4; ++k) {                                           \
            u32 q0 = e0 + p * 4 + k, q1 = e0 + 8 + p * 4 + k;                   \
            id[k]     = (q0 < end) ? __builtin_nontemporal_load(csr + q0) : N;  \
            id[4 + k] = (q1 < end) ? __builtin_nontemporal_load(csr + q1) : N;  \
        }                                                                       \
    }                                                                           \
    for (; e0 < end;) {                                                         \
        u32 e1 = e0 + 16;                                                       \
        int idn[8];                                                             \
        if (e1 < end) {                                                         \
            _Pragma("unroll")                                                   \
            for (int k = 0; k < 4; ++k) {                                       \
                u32 q0 = e1 + p * 4 + k, q1 = e1 + 8 + p * 4 + k;               \
                idn[k]     = (q0 < end) ? __builtin_nontemporal_load(csr + q0) : N; \
                idn[4 + k] = (q1 < end) ? __builtin_nontemporal_load(csr + q1) : N; \
            }                                                                   \
        }                                                                       \
        _Pragma("unroll")                                                       \
        for (int h = 0; h < 2; ++h) {                                           \
            int sj[8]; uint4 w[8];                                              \
            _Pragma("unroll")                                                   \
            for (int j = 0; j < 8; ++j)                                         \
                sj[j] = __shfl(id[h * 4 + (j & 3)], pairbase + (j >> 2));       \
            _Pragma("unroll")                                                   \
            for (int j = 0; j < 8; ++j) w[j] = base[(size_t)sj[j] * 2];         \
            _Pragma("unroll")                                                   \
            for (int j = 0; j < 8; ++j) {                                       \
                a0 += bflo(w[j].x); a1 += bfhi(w[j].x);                         \
                a2 += bflo(w[j].y); a3 += bfhi(w[j].y);                         \
                a4 += bflo(w[j].z); a5 += bfhi(w[j].z);                         \
                a6 += bflo(w[j].w); a7 += bfhi(w[j].w);                         \
            }                                                                   \
        }                                                                       \
        _Pragma("unroll")                                                       \
        for (int k = 0; k < 8; ++k) id[k] = idn[k];                             \
        e0 = e1;                                                                \
    }

// ---------------- gatherY: y[n][128] = bf16(dd*(xs[n] + sum xs[s])) ---------
// blockIdx%8 = slice -> all blocks of a slice land on one XCD; slice (3.2MB)
// stays L2-resident across its ~17x reuse.
__global__ __launch_bounds__(256) void gatherY(const u32* __restrict__ xsP,
                                               const int* __restrict__ csr,
                                               const u32* __restrict__ rowstart,
                                               const float* __restrict__ dis,
                                               u16* __restrict__ y, int N) {
    int tid = threadIdx.x;
    u32 bid = blockIdx.x;
    int s = bid & 7;
    int p = tid & 1;
    int node = (int)(bid >> 3) * 128 + (tid >> 1);
    bool live = node < N;
    int nodeC = live ? node : 0;
    float dd = dis[nodeC];
    u32 beg = rowstart[nodeC];
    u32 end = live ? rowstart[nodeC + 1] : beg;
    const uint4* base = (const uint4*)(xsP + (size_t)s * (N + 1) * 8) + p;

    uint4 selfv = base[(size_t)nodeC * 2];
    float a0 = bflo(selfv.x), a1 = bfhi(selfv.x);
    float a2 = bflo(selfv.y), a3 = bfhi(selfv.y);
    float a4 = bflo(selfv.z), a5 = bfhi(selfv.z);
    float a6 = bflo(selfv.w), a7 = bfhi(selfv.w);

    GATHER_SLICE()

    if (live) {
        u32x4 o;
        o.x = (u32)f2bf(a0 * dd) | ((u32)f2bf(a1 * dd) << 16);
        o.y = (u32)f2bf(a2 * dd) | ((u32)f2bf(a3 * dd) << 16);
        o.z = (u32)f2bf(a4 * dd) | ((u32)f2bf(a5 * dd) << 16);
        o.w = (u32)f2bf(a6 * dd) | ((u32)f2bf(a7 * dd) << 16);
        u32x4* dst = (u32x4*)(y + (size_t)node * 128 + s * 16 + p * 8);
        __builtin_nontemporal_store(o, dst);
    }
}

// ---------------- gemm1: tsP = bf16((y@Wf + bb)*dis) in paired slices -------
// tsP slice s holds cols {8s..8s+7} (mu) and {64+8s..64+8s+7} (ls):
// u16 tsP[s][(N+1)][16]. Row N preserved zero (aliases xsP zero row).
__global__ __launch_bounds__(256) void gemm1(const u16* __restrict__ y,
                                             const u16* __restrict__ WfT,
                                             const float* __restrict__ bb,
                                             const float* __restrict__ dis,
                                             u16* __restrict__ tsP, int N) {
    __shared__ __align__(16) u16 ytile[16][136];
    __shared__ float disS[16];
    int tid = threadIdx.x, blk = blockIdx.x;
    int node0 = blk * 16;
    if (tid < 16) disS[tid] = (node0 + tid < N) ? dis[node0 + tid] : 0.f;
    int row = tid >> 4, ch = tid & 15;
    int gn = node0 + row;
    int gnC = (gn < N) ? gn : (N - 1);
    uint4 av = ((const uint4*)y)[(size_t)gnC * 16 + ch];
    *(uint4*)&ytile[row][ch * 8] = av;
    __syncthreads();

    int wave = tid >> 6, lane = tid & 63, quad = lane >> 4, mn = lane & 15;
    bf16x8 af[4];
#pragma unroll
    for (int kk = 0; kk < 4; ++kk)
        af[kk] = *reinterpret_cast<const bf16x8*>(&ytile[mn][kk * 32 + quad * 8]);

#pragma unroll
    for (int n0 = 0; n0 < 2; ++n0) {
        int col = wave * 32 + n0 * 16 + mn;
        f32x4 acc = {0.f, 0.f, 0.f, 0.f};
#pragma unroll
        for (int kk = 0; kk < 4; ++kk) {
            bf16x8 bf =
                *reinterpret_cast<const bf16x8*>(&WfT[col * 128 + kk * 32 + quad * 8]);
            acc = __builtin_amdgcn_mfma_f32_16x16x32_bf16(af[kk], bf, acc, 0, 0, 0);
        }
        float bc = bb[col];
        int sC = (col < 64) ? (col >> 3) : ((col - 64) >> 3);
        int posC = (col & 7) + ((col < 64) ? 0 : 8);
        u16* op = tsP + ((size_t)sC * (N + 1) + node0) * 16 + posC;
#pragma unroll
        for (int r = 0; r < 4; ++r) {  // C/D: col=lane&15(+16*n0), row=quad*4+r
            int rr = quad * 4 + r;
            if (node0 + rr < N)
                __builtin_nontemporal_store(f2bf((acc[r] + bc) * disS[rr]),
                                            op + (size_t)rr * 16);
        }
    }
}

// ---------------- gatherZ: out = dd*(ts[d]+sum ts[s]) + bcat + reparam ------
// Same sliced skeleton; p=0 lane owns mu chunk (cols 8s..), p=1 owns ls chunk
// (cols 64+8s..). z = mu + eps*exp(ls) via one intra-pair shuffle.
__global__ __launch_bounds__(256) void gatherZ(const u32* __restrict__ tsP,
                                               const int* __restrict__ csr,
                                               const u32* __restrict__ rowstart,
                                               const float* __restrict__ dis,
                                               const float* __restrict__ bcat,
                                               const float* __restrict__ eps,
                                               float* __restrict__ out, int N) {
    int tid = threadIdx.x;
    u32 bid = blockIdx.x;
    int s = bid & 7;
    int p = tid & 1;
    int node = (int)(bid >> 3) * 128 + (tid >> 1);
    bool live = node < N;
    int nodeC = live ? node : 0;
    float dd = dis[nodeC];
    u32 beg = rowstart[nodeC];
    u32 end = live ? rowstart[nodeC + 1] : beg;
    const uint4* base = (const uint4*)(tsP + (size_t)s * (N + 1) * 8) + p;

    uint4 selfv = base[(size_t)nodeC * 2];
    float a0 = bflo(selfv.x), a1 = bfhi(selfv.x);
    float a2 = bflo(selfv.y), a3 = bfhi(selfv.y);
    float a4 = bflo(selfv.z), a5 = bfhi(selfv.z);
    float a6 = bflo(selfv.w), a7 = bfhi(selfv.w);

    GATHER_SLICE()

    const f32x4* bc = (const f32x4*)(bcat + (p ? 64 + 8 * s : 8 * s));
    f32x4 c0 = bc[0], c1 = bc[1];
    float v0 = a0 * dd + c0[0], v1 = a1 * dd + c0[1];
    float v2 = a2 * dd + c0[2], v3 = a3 * dd + c0[3];
    float v4 = a4 * dd + c1[0], v5 = a5 * dd + c1[1];
    float v6 = a6 * dd + c1[2], v7 = a7 * dd + c1[3];

    // ls values live on the odd lane of the pair.
    int lsrc = (tid & 63) | 1;
    float w0 = __shfl(v0, lsrc), w1 = __shfl(v1, lsrc), w2 = __shfl(v2, lsrc),
          w3 = __shfl(v3, lsrc), w4 = __shfl(v4, lsrc), w5 = __shfl(v5, lsrc),
          w6 = __shfl(v6, lsrc), w7 = __shfl(v7, lsrc);

    if (!live) return;
    long NO = (long)N * 64;
    if (p == 0) {  // mu cols 8s..8s+7 ; also compute z
        float* mu = out + NO + (long)node * 64 + 8 * s;
        __builtin_nontemporal_store(f32x4{v0, v1, v2, v3}, (f32x4*)mu);
        __builtin_nontemporal_store(f32x4{v4, v5, v6, v7}, (f32x4*)mu + 1);
        const f32x4* ep = (const f32x4*)(eps + (long)node * 64 + 8 * s);
        f32x4 e0v = __builtin_nontemporal_load(ep);
        f32x4 e1v = __builtin_nontemporal_load(ep + 1);
        float* z = out + (long)node * 64 + 8 * s;
        f32x4 z0 = {v0 + e0v[0] * __expf(w0), v1 + e0v[1] * __expf(w1),
                    v2 + e0v[2] * __expf(w2), v3 + e0v[3] * __expf(w3)};
        f32x4 z1 = {v4 + e1v[0] * __expf(w4), v5 + e1v[1] * __expf(w5),
                    v6 + e1v[2] * __expf(w6), v7 + e1v[3] * __expf(w7)};
        __builtin_nontemporal_store(z0, (f32x4*)z);
        __builtin_nontemporal_store(z1, (f32x4*)z + 1);
    } else {       // logstd cols 8s..8s+7 of ls block
        float* ls = out + 2 * NO + (long)node * 64 + 8 * s;
        __builtin_nontemporal_store(f32x4{v0, v1, v2, v3}, (f32x4*)ls);
        __builtin_nontemporal_store(f32x4{v4, v5, v6, v7}, (f32x4*)ls + 1);
    }
}

// ---------------------------------------------------------------------------
extern "C" void kernel_launch(void* const* d_in, const int* in_sizes, int n_in,
                              void* d_out, int out_size, void* d_ws, size_t ws_size,
                              hipStream_t stream) {
    const float* x   = (const float*)d_in[0];
    const int* ei    = (const int*)d_in[1];
    const float* W1  = (const float*)d_in[2];
    const float* b1  = (const float*)d_in[3];
    const float* Wmu = (const float*)d_in[4];
    const float* bmu = (const float*)d_in[5];
    const float* Wls = (const float*)d_in[6];
    const float* bls = (const float*)d_in[7];
    const float* eps = (const float*)d_in[8];
    float* out = (float*)d_out;

    const int N = in_sizes[0] / 128;   // 100000
    const int E = in_sizes[1] / 2;     // 1600000
    const int* src = ei;
    const int* dst = ei + E;
    const int NB = (N + 255) / 256;    // 391

    // WS layout (bytes), total ~60.44 MB (same footprint as round 8).
    char* ws = (char*)d_ws;
    u32* deg       = (u32*)(ws + 0);         //   400,000
    u32* rowstart  = (u32*)(ws + 401408);    //   400,004
    u32* blockSums = (u32*)(ws + 802816);    //     2,048
    u32* blockOffs = (u32*)(ws + 804864);    //     2,048
    float* dis     = (float*)(ws + 806912);  //   400,000
    u16* WfT       = (u16*)(ws + 1208320);   //    32,768 (bf16, transposed)
    float* bb      = (float*)(ws + 1241088); //       512
    float* bcat    = (float*)(ws + 1241600); //       512
    u8* loc        = (u8*)(ws + 1242112);    // 1,600,000
    int* csr       = (int*)(ws + 2842112);   // 6,400,000
    u32* xsP       = (u32*)(ws + 9242112);   // 25,600,256 (8 slices x (N+1)x32B)
    u16* y         = (u16*)(ws + 34842368);  // 25,600,000 (N x 128 bf16)
    u16* tsP       = (u16*)xsP;              // alias: xsP dead after gatherY;
                                             // zero row N survives for gatherZ.

    hipMemsetAsync(deg, 0, 400000, stream);

    int gridE4 = (E / 4 + 255) / 256;
    deg_hist<<<gridE4, 256, 0, stream>>>(dst, deg, loc, E);
    scanA<<<NB, 256, 0, stream>>>(deg, blockSums, N);
    scanB<<<1, 512, 0, stream>>>(blockSums, blockOffs, NB);
    scanC<<<NB, 256, 0, stream>>>(deg, blockOffs, rowstart, dis, N, E);
    place_kernel<<<gridE4, 256, 0, stream>>>(src, dst, loc, rowstart, csr, E);
    fuse_w<<<64, 256, 0, stream>>>(W1, Wmu, Wls, b1, bmu, bls, WfT, bb, bcat);

    long Qc = (long)(N + 1) * 32;
    convert_x<<<(int)((Qc + 255) / 256), 256, 0, stream>>>(x, dis, xsP, N);

    int gridS = 8 * ((N + 127) / 128);            // slice = blockIdx % 8
    gatherY<<<gridS, 256, 0, stream>>>(xsP, csr, rowstart, dis, y, N);

    gemm1<<<(N + 15) / 16, 256, 0, stream>>>(y, WfT, bb, dis, tsP, N);

    gatherZ<<<gridS, 256, 0, stream>>>((const u32*)tsP, csr, rowstart, dis,
                                       bcat, eps, out, N);
}

// Round 3
// 421.680 us; speedup vs baseline: 1.5268x; 1.5268x over previous
//
#include <hip/hip_runtime.h>
#include <hip/hip_bf16.h>

// ---------------------------------------------------------------------------
// GraphEncoder (VGAE 2-layer GCN + reparam), fp32 in/out, edge_index int32.
// Round 11 (= round 10 + compile fix: nontemporal builtins need native
// ext_vector types, not HIP_vector_type int4/uchar4).
//  * gathers: full 16-deep uint4 staging (was 8+8 in round 8) -> second
//    half's loads no longer wait behind first half's vmcnt consumption.
//  * nontemporal on write-once/read-once streams (out, eps, ts-store,
//    deg_hist/place streaming reads) so they stop evicting the gather tables
//    from L2. csr scattered stores stay cached (need line merging).
// Math: ts = ((Anorm@x)@Wf + 1(x)bb)*dis ; [mu|ls] = dd*(ts[d]+sum ts[s])+bcat
//       Wf = W1@[Wmu|Wls], bb = b1@[Wmu|Wls]  (rowsum-bias identity).
// ---------------------------------------------------------------------------

typedef unsigned int u32;
typedef unsigned short u16;
typedef unsigned char u8;
typedef __bf16 bf16x8 __attribute__((ext_vector_type(8)));
typedef float f32x4 __attribute__((ext_vector_type(4)));
typedef int i32x4 __attribute__((ext_vector_type(4)));

__device__ __forceinline__ u16 f2bf(float f) {  // fp32 -> bf16 RNE
    union { float f; u32 u; } v; v.f = f;
    u32 u = v.u;
    u += 0x7fffu + ((u >> 16) & 1u);
    return (u16)(u >> 16);
}
__device__ __forceinline__ float bflo(u32 p) {
    union { u32 u; float f; } v; v.u = p << 16; return v.f;
}
__device__ __forceinline__ float bfhi(u32 p) {
    union { u32 u; float f; } v; v.u = p & 0xffff0000u; return v.f;
}

// ---------------- degree histogram + per-edge u8 local offset (x4) ----------
__global__ __launch_bounds__(256) void deg_hist(const int* __restrict__ dst,
                                                u32* __restrict__ deg,
                                                u8* __restrict__ loc, int E) {
    int i4 = (blockIdx.x * 256 + threadIdx.x) * 4;
    if (i4 + 3 < E) {
        i32x4 d4 = __builtin_nontemporal_load((const i32x4*)(dst + i4));
        u32 l0 = atomicAdd(&deg[d4.x], 1u) & 0xffu;
        u32 l1 = atomicAdd(&deg[d4.y], 1u) & 0xffu;
        u32 l2 = atomicAdd(&deg[d4.z], 1u) & 0xffu;
        u32 l3 = atomicAdd(&deg[d4.w], 1u) & 0xffu;
        u32 packed = l0 | (l1 << 8) | (l2 << 16) | (l3 << 24);
        __builtin_nontemporal_store(packed, (u32*)(loc + i4));
    } else {
        for (int i = i4; i < E; ++i) loc[i] = (u8)atomicAdd(&deg[dst[i]], 1u);
    }
}

// ---------------- scan A: per-block totals ----------------
__global__ __launch_bounds__(256) void scanA(const u32* __restrict__ deg,
                                             u32* __restrict__ blockSums, int N) {
    __shared__ u32 s[256];
    int t = threadIdx.x, i = blockIdx.x * 256 + t;
    s[t] = (i < N) ? deg[i] : 0u;
    for (int off = 128; off > 0; off >>= 1) {
        __syncthreads();
        if (t < off) s[t] += s[t + off];
    }
    if (t == 0) blockSums[blockIdx.x] = s[0];
}

// ---------------- scan B: exclusive scan of block totals (1 block) ----------
__global__ __launch_bounds__(512) void scanB(const u32* __restrict__ blockSums,
                                             u32* __restrict__ blockOffs, int NB) {
    __shared__ u32 s[512];
    int t = threadIdx.x;
    u32 v = (t < NB) ? blockSums[t] : 0u;
    s[t] = v;
    for (int off = 1; off < 512; off <<= 1) {
        __syncthreads();
        u32 add = (t >= off) ? s[t - off] : 0u;
        __syncthreads();
        s[t] += add;
    }
    __syncthreads();
    if (t < NB) blockOffs[t] = s[t] - v;  // exclusive
}

// ---------------- scan C: rowstart + dis ----------------
__global__ __launch_bounds__(256) void scanC(const u32* __restrict__ deg,
                                             const u32* __restrict__ blockOffs,
                                             u32* __restrict__ rowstart,
                                             float* __restrict__ dis, int N, int E) {
    __shared__ u32 s[256];
    int t = threadIdx.x, i = blockIdx.x * 256 + t;
    u32 v = (i < N) ? deg[i] : 0u;
    s[t] = v;
    for (int off = 1; off < 256; off <<= 1) {
        __syncthreads();
        u32 add = (t >= off) ? s[t - off] : 0u;
        __syncthreads();
        s[t] += add;
    }
    __syncthreads();
    if (i < N) {
        rowstart[i] = blockOffs[blockIdx.x] + s[t] - v;  // exclusive
        dis[i] = rsqrtf((float)v + 1.0f);
    }
    if (i == 0) rowstart[N] = (u32)E;
}

// ---------------- CSR placement (x4, pure scattered store) ------------------
__global__ __launch_bounds__(256) void place_kernel(const int* __restrict__ src,
                                                    const int* __restrict__ dst,
                                                    const u8* __restrict__ loc,
                                                    const u32* __restrict__ rowstart,
                                                    int* __restrict__ csr, int E) {
    int i4 = (blockIdx.x * 256 + threadIdx.x) * 4;
    if (i4 + 3 < E) {
        i32x4 s4 = __builtin_nontemporal_load((const i32x4*)(src + i4));
        i32x4 d4 = __builtin_nontemporal_load((const i32x4*)(dst + i4));
        u32 l4 = __builtin_nontemporal_load((const u32*)(loc + i4));
        csr[rowstart[d4.x] + (l4 & 0xffu)] = s4.x;
        csr[rowstart[d4.y] + ((l4 >> 8) & 0xffu)] = s4.y;
        csr[rowstart[d4.z] + ((l4 >> 16) & 0xffu)] = s4.z;
        csr[rowstart[d4.w] + (l4 >> 24)] = s4.w;
    } else {
        for (int i = i4; i < E; ++i) csr[rowstart[dst[i]] + loc[i]] = src[i];
    }
}

// ---------------- fuse weights: WfT(bf16) = (W1@[Wmu|Wls])^T, bb, bcat ------
__global__ __launch_bounds__(256) void fuse_w(const float* __restrict__ W1,
                                              const float* __restrict__ Wmu,
                                              const float* __restrict__ Wls,
                                              const float* __restrict__ b1,
                                              const float* __restrict__ bmu,
                                              const float* __restrict__ bls,
                                              u16* __restrict__ WfT,
                                              float* __restrict__ bb,
                                              float* __restrict__ bcat) {
    int idx = blockIdx.x * 256 + threadIdx.x;  // 16384
    if (idx >= 16384) return;
    int k = idx >> 7, n = idx & 127;
    const float* Wcol = (n < 64) ? (Wmu + n) : (Wls + (n - 64));
    float acc = 0.f;
#pragma unroll 8
    for (int j = 0; j < 128; ++j) acc += W1[k * 128 + j] * Wcol[j * 64];
    WfT[n * 128 + k] = f2bf(acc);  // transposed, bf16
    if (k == 0) {
        float accb = 0.f;
#pragma unroll 8
        for (int j = 0; j < 128; ++j) accb += b1[j] * Wcol[j * 64];
        bb[n] = accb;
        bcat[n] = (n < 64) ? bmu[n] : bls[n - 64];
    }
}

// ---------------- xs = bf16(x * dis[node]) ; zero row N in xs and ts --------
__global__ __launch_bounds__(256) void convert_x(const float* __restrict__ x,
                                                 const float* __restrict__ dis,
                                                 u32* __restrict__ xs,
                                                 u32* __restrict__ ts, int N) {
    long i = (long)blockIdx.x * 256 + threadIdx.x;  // (N+1)*32 threads
    long node = i >> 5;
    if (node > N) return;
    if (node == N) {  // zero row for branch-free dummy reads
        ((uint2*)xs)[i] = make_uint2(0u, 0u);
        ((uint2*)ts)[i] = make_uint2(0u, 0u);
        return;
    }
    float dd = dis[node];
    f32x4 v = ((const f32x4*)x)[i];
    u32 p0 = (u32)f2bf(v[0] * dd) | ((u32)f2bf(v[1] * dd) << 16);
    u32 p1 = (u32)f2bf(v[2] * dd) | ((u32)f2bf(v[3] * dd) << 16);
    ((uint2*)xs)[i] = make_uint2(p0, p1);
}

// ---------------- fused gather1 + GEMM + bb + dis-scale ---------------------
// Block = 16 nodes. Phase 1: gather y = xs[d] + sum xs[s] (4 nodes/wave,
// 16 lanes/node, FULL 16-deep staged uint4 loads, csr prefetch) -> bf16 LDS
// tile (scaled by dd). Phase 2: ts[16x128] = bf16((y@Wf + bb) * dis) via
// MFMA, wave w covers cols [32w,32w+32), B-frags from L1-resident WfT.
__global__ __launch_bounds__(256) void g1gemm(const u32* __restrict__ xs,
                                              const int* __restrict__ csr,
                                              const u32* __restrict__ rowstart,
                                              const float* __restrict__ dis,
                                              const u16* __restrict__ WfT,
                                              const float* __restrict__ bb,
                                              u16* __restrict__ ts, int N) {
    __shared__ __align__(16) u16 ytile[16][136];  // 272B rows (16B aligned)
    __shared__ float disS[16];
    int tid = threadIdx.x, blk = blockIdx.x;
    int wave = tid >> 6, lane = tid & 63;
    int sub = lane >> 4, l = lane & 15;
    int nl = wave * 4 + sub;          // node_local 0..15
    int node = blk * 16 + nl;
    bool live = node < N;
    int nodeC = live ? node : 0;
    float dd = dis[nodeC];
    u32 beg = live ? rowstart[nodeC] : 0u;
    u32 end = live ? rowstart[nodeC + 1] : 0u;
    if (tid < 16) disS[tid] = (blk * 16 + tid < N) ? dis[blk * 16 + tid] : 0.f;

    const uint4* xs4 = (const uint4*)xs;
    uint4 selfv = xs4[(long)nodeC * 16 + l];
    float a0 = bflo(selfv.x), a1 = bfhi(selfv.x);
    float a2 = bflo(selfv.y), a3 = bfhi(selfv.y);
    float a4 = bflo(selfv.z), a5 = bfhi(selfv.z);
    float a6 = bflo(selfv.w), a7 = bfhi(selfv.w);

    int s = (beg + (u32)l < end) ? csr[beg + l] : N;
    for (u32 e0 = beg; e0 < end; e0 += 16) {
        u32 e1 = e0 + 16;
        int sn = (e1 < end && e1 + (u32)l < end) ? csr[e1 + l] : N;
        uint4 w[16];
#pragma unroll
        for (int j = 0; j < 16; ++j) {
            int sj = __shfl(s, sub * 16 + j);
            w[j] = xs4[(long)sj * 16 + l];
        }
#pragma unroll
        for (int j = 0; j < 16; ++j) {
            a0 += bflo(w[j].x); a1 += bfhi(w[j].x);
            a2 += bflo(w[j].y); a3 += bfhi(w[j].y);
            a4 += bflo(w[j].z); a5 += bfhi(w[j].z);
            a6 += bflo(w[j].w); a7 += bfhi(w[j].w);
        }
        s = sn;
    }
    uint4 o = make_uint4(0u, 0u, 0u, 0u);
    if (live) {
        o.x = (u32)f2bf(a0 * dd) | ((u32)f2bf(a1 * dd) << 16);
        o.y = (u32)f2bf(a2 * dd) | ((u32)f2bf(a3 * dd) << 16);
        o.z = (u32)f2bf(a4 * dd) | ((u32)f2bf(a5 * dd) << 16);
        o.w = (u32)f2bf(a6 * dd) | ((u32)f2bf(a7 * dd) << 16);
    }
    *(uint4*)&ytile[nl][l * 8] = o;
    __syncthreads();

    // ---- MFMA phase: rows 0..15 (shared), cols wave*32 .. wave*32+31 ----
    int quad = sub, mn = l;
    bf16x8 af[4];  // A[m=mn][k = kk*32 + quad*8 + j]
#pragma unroll
    for (int kk = 0; kk < 4; ++kk)
        af[kk] = *reinterpret_cast<const bf16x8*>(&ytile[mn][kk * 32 + quad * 8]);

#pragma unroll
    for (int n0 = 0; n0 < 2; ++n0) {
        int col = wave * 32 + n0 * 16 + mn;
        f32x4 acc = {0.f, 0.f, 0.f, 0.f};
#pragma unroll
        for (int kk = 0; kk < 4; ++kk) {
            bf16x8 bf =
                *reinterpret_cast<const bf16x8*>(&WfT[col * 128 + kk * 32 + quad * 8]);
            acc = __builtin_amdgcn_mfma_f32_16x16x32_bf16(af[kk], bf, acc, 0, 0, 0);
        }
        float bc = bb[col];
#pragma unroll
        for (int r = 0; r < 4; ++r) {  // C/D: col=lane&15(+16*n0), row=quad*4+r
            int row = quad * 4 + r;
            int gn = blk * 16 + row;
            if (gn < N)
                __builtin_nontemporal_store(f2bf((acc[r] + bc) * disS[row]),
                                            ts + (long)gn * 128 + col);
        }
    }
}

// ---------------- gather2 + bcat + reparam ----------------------------------
// val = dd*(ts[d] + sum_s ts[s]) + bcat ; cols 0..63 mu, 64..127 ls.
__global__ __launch_bounds__(256) void gather2(const u32* __restrict__ ts,
                                               const int* __restrict__ csr,
                                               const u32* __restrict__ rowstart,
                                               const float* __restrict__ dis,
                                               const float* __restrict__ bcat,
                                               const float* __restrict__ eps,
                                               float* __restrict__ out, int N) {
    int wid = (blockIdx.x * 256 + threadIdx.x) >> 6;
    int sub = (threadIdx.x & 63) >> 4, l = threadIdx.x & 15;
    int node = wid * 4 + sub;
    bool live = node < N;
    int nodeC = live ? node : 0;
    float dd = dis[nodeC];
    u32 beg = live ? rowstart[nodeC] : 0u;
    u32 end = live ? rowstart[nodeC + 1] : 0u;
    const uint4* ts4 = (const uint4*)ts;

    uint4 selfv = ts4[(long)nodeC * 16 + l];
    float a0 = bflo(selfv.x), a1 = bfhi(selfv.x);
    float a2 = bflo(selfv.y), a3 = bfhi(selfv.y);
    float a4 = bflo(selfv.z), a5 = bfhi(selfv.z);
    float a6 = bflo(selfv.w), a7 = bfhi(selfv.w);

    int s = (beg + (u32)l < end) ? csr[beg + l] : N;
    for (u32 e0 = beg; e0 < end; e0 += 16) {
        u32 e1 = e0 + 16;
        int sn = (e1 < end && e1 + (u32)l < end) ? csr[e1 + l] : N;
        uint4 w[16];
#pragma unroll
        for (int j = 0; j < 16; ++j) {
            int sj = __shfl(s, sub * 16 + j);
            w[j] = ts4[(long)sj * 16 + l];
        }
#pragma unroll
        for (int j = 0; j < 16; ++j) {
            a0 += bflo(w[j].x); a1 += bfhi(w[j].x);
            a2 += bflo(w[j].y); a3 += bfhi(w[j].y);
            a4 += bflo(w[j].z); a5 += bfhi(w[j].z);
            a6 += bflo(w[j].w); a7 += bfhi(w[j].w);
        }
        s = sn;
    }

    int c0 = l * 8;  // cols c0..c0+7 (l<8: mu cols c0; l>=8: ls cols c0-64)
    f32x4 clo = ((const f32x4*)bcat)[2 * l], chi = ((const f32x4*)bcat)[2 * l + 1];
    float v0 = a0 * dd + clo[0];
    float v1 = a1 * dd + clo[1];
    float v2 = a2 * dd + clo[2];
    float v3 = a3 * dd + clo[3];
    float v4 = a4 * dd + chi[0];
    float v5 = a5 * dd + chi[1];
    float v6 = a6 * dd + chi[2];
    float v7 = a7 * dd + chi[3];

    // ls values live 8 lanes up within the wave (same subgroup, l+8).
    int srcl = (threadIdx.x & 63) + 8;
    float w0 = __shfl(v0, srcl), w1 = __shfl(v1, srcl), w2 = __shfl(v2, srcl),
          w3 = __shfl(v3, srcl), w4 = __shfl(v4, srcl), w5 = __shfl(v5, srcl),
          w6 = __shfl(v6, srcl), w7 = __shfl(v7, srcl);

    if (!live) return;
    long NO = (long)N * 64;
    if (l < 8) {  // mu cols c0..c0+7 ; also compute z
        float* mu = out + NO + (long)node * 64 + c0;
        __builtin_nontemporal_store(f32x4{v0, v1, v2, v3}, (f32x4*)mu);
        __builtin_nontemporal_store(f32x4{v4, v5, v6, v7}, (f32x4*)mu + 1);
        const f32x4* ep = (const f32x4*)(eps + (long)node * 64 + c0);
        f32x4 e0v = __builtin_nontemporal_load(ep);
        f32x4 e1v = __builtin_nontemporal_load(ep + 1);
        float* z = out + (long)node * 64 + c0;
        f32x4 z0 = {v0 + e0v[0] * __expf(w0), v1 + e0v[1] * __expf(w1),
                    v2 + e0v[2] * __expf(w2), v3 + e0v[3] * __expf(w3)};
        f32x4 z1 = {v4 + e1v[0] * __expf(w4), v5 + e1v[1] * __expf(w5),
                    v6 + e1v[2] * __expf(w6), v7 + e1v[3] * __expf(w7)};
        __builtin_nontemporal_store(z0, (f32x4*)z);
        __builtin_nontemporal_store(z1, (f32x4*)z + 1);
    } else {      // logstd cols (c0-64)..(c0-64+7)
        float* ls = out + 2 * NO + (long)node * 64 + (c0 - 64);
        __builtin_nontemporal_store(f32x4{v0, v1, v2, v3}, (f32x4*)ls);
        __builtin_nontemporal_store(f32x4{v4, v5, v6, v7}, (f32x4*)ls + 1);
    }
}

// ---------------------------------------------------------------------------
extern "C" void kernel_launch(void* const* d_in, const int* in_sizes, int n_in,
                              void* d_out, int out_size, void* d_ws, size_t ws_size,
                              hipStream_t stream) {
    const float* x   = (const float*)d_in[0];
    const int* ei    = (const int*)d_in[1];
    const float* W1  = (const float*)d_in[2];
    const float* b1  = (const float*)d_in[3];
    const float* Wmu = (const float*)d_in[4];
    const float* bmu = (const float*)d_in[5];
    const float* Wls = (const float*)d_in[6];
    const float* bls = (const float*)d_in[7];
    const float* eps = (const float*)d_in[8];
    float* out = (float*)d_out;

    const int N = in_sizes[0] / 128;   // 100000
    const int E = in_sizes[1] / 2;     // 1600000
    const int* src = ei;
    const int* dst = ei + E;
    const int NB = (N + 255) / 256;    // 391

    // WS layout (bytes), total ~60.4 MB.
    char* ws = (char*)d_ws;
    u32* deg       = (u32*)(ws + 0);         //   400,000
    u32* rowstart  = (u32*)(ws + 401408);    //   400,004
    u32* blockSums = (u32*)(ws + 802816);    //     2,048
    u32* blockOffs = (u32*)(ws + 804864);    //     2,048
    float* dis     = (float*)(ws + 806912);  //   400,000
    u16* WfT       = (u16*)(ws + 1208320);   //    32,768 (bf16, transposed)
    float* bb      = (float*)(ws + 1241088); //       512
    float* bcat    = (float*)(ws + 1241600); //       512
    u8* loc        = (u8*)(ws + 1242112);    // 1,600,000
    int* csr       = (int*)(ws + 2842112);   // 6,400,000
    u32* xs        = (u32*)(ws + 9242112);   // 25,600,256 ((N+1) rows bf16)
    u32* ts        = (u32*)(ws + 34842368);  // 25,600,256 ((N+1) rows bf16)

    hipMemsetAsync(deg, 0, 400000, stream);

    int gridE4 = (E / 4 + 255) / 256;
    deg_hist<<<gridE4, 256, 0, stream>>>(dst, deg, loc, E);
    scanA<<<NB, 256, 0, stream>>>(deg, blockSums, N);
    scanB<<<1, 512, 0, stream>>>(blockSums, blockOffs, NB);
    scanC<<<NB, 256, 0, stream>>>(deg, blockOffs, rowstart, dis, N, E);
    place_kernel<<<gridE4, 256, 0, stream>>>(src, dst, loc, rowstart, csr, E);
    fuse_w<<<64, 256, 0, stream>>>(W1, Wmu, Wls, b1, bmu, bls, WfT, bb, bcat);

    long Qc = (long)(N + 1) * 32;  // uint2-granular threads incl. zero row
    convert_x<<<(int)((Qc + 255) / 256), 256, 0, stream>>>(x, dis, xs, ts, N);

    int gridT = (N + 15) / 16;                    // 16 nodes per block
    g1gemm<<<gridT, 256, 0, stream>>>(xs, csr, rowstart, dis, WfT, bb,
                                      (u16*)ts, N);

    int gridG = ((N + 3) / 4 * 64 + 255) / 256;   // 1 wave / 4 nodes
    gather2<<<gridG, 256, 0, stream>>>(ts, csr, rowstart, dis, bcat, eps, out, N);
}

// Round 4
// 411.330 us; speedup vs baseline: 1.5653x; 1.0252x over previous
//
#include <hip/hip_runtime.h>
#include <hip/hip_bf16.h>

// ---------------------------------------------------------------------------
// GraphEncoder (VGAE 2-layer GCN + reparam), fp32 in/out, edge_index int32.
// Round 12: dual-subgroup gathers (wave-level memory parallelism).
//  * Gathers: 2 nodes/wave, 2 independent 16-lane subgroups per node, each
//    owning a contiguous half of the node's edge range, 8-edge chunks with
//    8-deep uint4 staging + next-chunk csr prefetch. Doubles rows-in-flight
//    per node (compiler capped source-level staging at ~8 — VGPR stayed 68
//    in rounds 8/11), doubles wave count, and halves max-degree divergence
//    (max over 2 nodes, half-ranges). Partials merged via shfl_xor(16).
//  * g1gemm: 512-thread blocks (16 nodes); MFMA phase = 8 waves x 16 cols.
//  * nt stream hints kept from round 11 (measured neutral).
// Math: ts = ((Anorm@x)@Wf + 1(x)bb)*dis ; [mu|ls] = dd*(ts[d]+sum ts[s])+bcat
//       Wf = W1@[Wmu|Wls], bb = b1@[Wmu|Wls]  (rowsum-bias identity).
// ---------------------------------------------------------------------------

typedef unsigned int u32;
typedef unsigned short u16;
typedef unsigned char u8;
typedef __bf16 bf16x8 __attribute__((ext_vector_type(8)));
typedef float f32x4 __attribute__((ext_vector_type(4)));
typedef int i32x4 __attribute__((ext_vector_type(4)));

__device__ __forceinline__ u16 f2bf(float f) {  // fp32 -> bf16 RNE
    union { float f; u32 u; } v; v.f = f;
    u32 u = v.u;
    u += 0x7fffu + ((u >> 16) & 1u);
    return (u16)(u >> 16);
}
__device__ __forceinline__ float bflo(u32 p) {
    union { u32 u; float f; } v; v.u = p << 16; return v.f;
}
__device__ __forceinline__ float bfhi(u32 p) {
    union { u32 u; float f; } v; v.u = p & 0xffff0000u; return v.f;
}

// ---------------- degree histogram + per-edge u8 local offset (x4) ----------
__global__ __launch_bounds__(256) void deg_hist(const int* __restrict__ dst,
                                                u32* __restrict__ deg,
                                                u8* __restrict__ loc, int E) {
    int i4 = (blockIdx.x * 256 + threadIdx.x) * 4;
    if (i4 + 3 < E) {
        i32x4 d4 = __builtin_nontemporal_load((const i32x4*)(dst + i4));
        u32 l0 = atomicAdd(&deg[d4.x], 1u) & 0xffu;
        u32 l1 = atomicAdd(&deg[d4.y], 1u) & 0xffu;
        u32 l2 = atomicAdd(&deg[d4.z], 1u) & 0xffu;
        u32 l3 = atomicAdd(&deg[d4.w], 1u) & 0xffu;
        u32 packed = l0 | (l1 << 8) | (l2 << 16) | (l3 << 24);
        __builtin_nontemporal_store(packed, (u32*)(loc + i4));
    } else {
        for (int i = i4; i < E; ++i) loc[i] = (u8)atomicAdd(&deg[dst[i]], 1u);
    }
}

// ---------------- scan A: per-block totals ----------------
__global__ __launch_bounds__(256) void scanA(const u32* __restrict__ deg,
                                             u32* __restrict__ blockSums, int N) {
    __shared__ u32 s[256];
    int t = threadIdx.x, i = blockIdx.x * 256 + t;
    s[t] = (i < N) ? deg[i] : 0u;
    for (int off = 128; off > 0; off >>= 1) {
        __syncthreads();
        if (t < off) s[t] += s[t + off];
    }
    if (t == 0) blockSums[blockIdx.x] = s[0];
}

// ---------------- scan B: exclusive scan of block totals (1 block) ----------
__global__ __launch_bounds__(512) void scanB(const u32* __restrict__ blockSums,
                                             u32* __restrict__ blockOffs, int NB) {
    __shared__ u32 s[512];
    int t = threadIdx.x;
    u32 v = (t < NB) ? blockSums[t] : 0u;
    s[t] = v;
    for (int off = 1; off < 512; off <<= 1) {
        __syncthreads();
        u32 add = (t >= off) ? s[t - off] : 0u;
        __syncthreads();
        s[t] += add;
    }
    __syncthreads();
    if (t < NB) blockOffs[t] = s[t] - v;  // exclusive
}

// ---------------- scan C: rowstart + dis ----------------
__global__ __launch_bounds__(256) void scanC(const u32* __restrict__ deg,
                                             const u32* __restrict__ blockOffs,
                                             u32* __restrict__ rowstart,
                                             float* __restrict__ dis, int N, int E) {
    __shared__ u32 s[256];
    int t = threadIdx.x, i = blockIdx.x * 256 + t;
    u32 v = (i < N) ? deg[i] : 0u;
    s[t] = v;
    for (int off = 1; off < 256; off <<= 1) {
        __syncthreads();
        u32 add = (t >= off) ? s[t - off] : 0u;
        __syncthreads();
        s[t] += add;
    }
    __syncthreads();
    if (i < N) {
        rowstart[i] = blockOffs[blockIdx.x] + s[t] - v;  // exclusive
        dis[i] = rsqrtf((float)v + 1.0f);
    }
    if (i == 0) rowstart[N] = (u32)E;
}

// ---------------- CSR placement (x4, pure scattered store) ------------------
__global__ __launch_bounds__(256) void place_kernel(const int* __restrict__ src,
                                                    const int* __restrict__ dst,
                                                    const u8* __restrict__ loc,
                                                    const u32* __restrict__ rowstart,
                                                    int* __restrict__ csr, int E) {
    int i4 = (blockIdx.x * 256 + threadIdx.x) * 4;
    if (i4 + 3 < E) {
        i32x4 s4 = __builtin_nontemporal_load((const i32x4*)(src + i4));
        i32x4 d4 = __builtin_nontemporal_load((const i32x4*)(dst + i4));
        u32 l4 = __builtin_nontemporal_load((const u32*)(loc + i4));
        csr[rowstart[d4.x] + (l4 & 0xffu)] = s4.x;
        csr[rowstart[d4.y] + ((l4 >> 8) & 0xffu)] = s4.y;
        csr[rowstart[d4.z] + ((l4 >> 16) & 0xffu)] = s4.z;
        csr[rowstart[d4.w] + (l4 >> 24)] = s4.w;
    } else {
        for (int i = i4; i < E; ++i) csr[rowstart[dst[i]] + loc[i]] = src[i];
    }
}

// ---------------- fuse weights: WfT(bf16) = (W1@[Wmu|Wls])^T, bb, bcat ------
__global__ __launch_bounds__(256) void fuse_w(const float* __restrict__ W1,
                                              const float* __restrict__ Wmu,
                                              const float* __restrict__ Wls,
                                              const float* __restrict__ b1,
                                              const float* __restrict__ bmu,
                                              const float* __restrict__ bls,
                                              u16* __restrict__ WfT,
                                              float* __restrict__ bb,
                                              float* __restrict__ bcat) {
    int idx = blockIdx.x * 256 + threadIdx.x;  // 16384
    if (idx >= 16384) return;
    int k = idx >> 7, n = idx & 127;
    const float* Wcol = (n < 64) ? (Wmu + n) : (Wls + (n - 64));
    float acc = 0.f;
#pragma unroll 8
    for (int j = 0; j < 128; ++j) acc += W1[k * 128 + j] * Wcol[j * 64];
    WfT[n * 128 + k] = f2bf(acc);  // transposed, bf16
    if (k == 0) {
        float accb = 0.f;
#pragma unroll 8
        for (int j = 0; j < 128; ++j) accb += b1[j] * Wcol[j * 64];
        bb[n] = accb;
        bcat[n] = (n < 64) ? bmu[n] : bls[n - 64];
    }
}

// ---------------- xs = bf16(x * dis[node]) ; zero row N in xs and ts --------
__global__ __launch_bounds__(256) void convert_x(const float* __restrict__ x,
                                                 const float* __restrict__ dis,
                                                 u32* __restrict__ xs,
                                                 u32* __restrict__ ts, int N) {
    long i = (long)blockIdx.x * 256 + threadIdx.x;  // (N+1)*32 threads
    long node = i >> 5;
    if (node > N) return;
    if (node == N) {  // zero row for branch-free dummy reads
        ((uint2*)xs)[i] = make_uint2(0u, 0u);
        ((uint2*)ts)[i] = make_uint2(0u, 0u);
        return;
    }
    float dd = dis[node];
    f32x4 v = ((const f32x4*)x)[i];
    u32 p0 = (u32)f2bf(v[0] * dd) | ((u32)f2bf(v[1] * dd) << 16);
    u32 p1 = (u32)f2bf(v[2] * dd) | ((u32)f2bf(v[3] * dd) << 16);
    ((uint2*)xs)[i] = make_uint2(p0, p1);
}

// ---------------- fused gather1 + GEMM + bb + dis-scale ---------------------
// Block = 512 threads = 16 nodes. Phase 1: 2 nodes/wave, 2 subgroups/node;
// subgroup h sums contiguous half [mybeg,myend) of the node's CSR range in
// 8-edge chunks (8-deep uint4 staging, idx prefetch); partials merged via
// shfl_xor(16) -> bf16 LDS tile (scaled by dd). Phase 2: ts[16x128] =
// bf16((y@Wf + bb) * dis) via MFMA, wave w covers cols [16w,16w+16).
__global__ __launch_bounds__(512) void g1gemm(const u32* __restrict__ xs,
                                              const int* __restrict__ csr,
                                              const u32* __restrict__ rowstart,
                                              const float* __restrict__ dis,
                                              const u16* __restrict__ WfT,
                                              const float* __restrict__ bb,
                                              u16* __restrict__ ts, int N) {
    __shared__ __align__(16) u16 ytile[16][136];  // 272B rows (16B aligned)
    __shared__ float disS[16];
    int tid = threadIdx.x, blk = blockIdx.x;
    int wave = tid >> 6, lane = tid & 63;
    int nsub = lane >> 5;          // node within wave (0..1)
    int h = (lane >> 4) & 1;       // subgroup within node (0..1)
    int l = lane & 15;             // lane within subgroup
    int nl = wave * 2 + nsub;      // node_local 0..15
    int node = blk * 16 + nl;
    bool live = node < N;
    int nodeC = live ? node : 0;
    float dd = dis[nodeC];
    u32 beg = live ? rowstart[nodeC] : 0u;
    u32 end = live ? rowstart[nodeC + 1] : 0u;
    u32 cut = beg + ((end - beg + 1u) >> 1);
    u32 mybeg = h ? cut : beg;
    u32 myend = h ? end : cut;
    if (tid < 16) disS[tid] = (blk * 16 + tid < N) ? dis[blk * 16 + tid] : 0.f;

    const uint4* xs4 = (const uint4*)xs;
    uint4 selfv = xs4[(long)nodeC * 16 + l];
    bool h0 = (h == 0);
    float a0 = h0 ? bflo(selfv.x) : 0.f, a1 = h0 ? bfhi(selfv.x) : 0.f;
    float a2 = h0 ? bflo(selfv.y) : 0.f, a3 = h0 ? bfhi(selfv.y) : 0.f;
    float a4 = h0 ? bflo(selfv.z) : 0.f, a5 = h0 ? bfhi(selfv.z) : 0.f;
    float a6 = h0 ? bflo(selfv.w) : 0.f, a7 = h0 ? bfhi(selfv.w) : 0.f;

    int sbase = nsub * 32 + h * 16;
    int s = (l < 8 && mybeg + (u32)l < myend) ? csr[mybeg + l] : N;
    for (u32 e0 = mybeg; e0 < myend; e0 += 8) {
        u32 e1 = e0 + 8;
        int sn = (l < 8 && e1 < myend && e1 + (u32)l < myend) ? csr[e1 + l] : N;
        uint4 w[8];
#pragma unroll
        for (int j = 0; j < 8; ++j) {
            int sj = __shfl(s, sbase + j);
            w[j] = xs4[(long)sj * 16 + l];
        }
#pragma unroll
        for (int j = 0; j < 8; ++j) {
            a0 += bflo(w[j].x); a1 += bfhi(w[j].x);
            a2 += bflo(w[j].y); a3 += bfhi(w[j].y);
            a4 += bflo(w[j].z); a5 += bfhi(w[j].z);
            a6 += bflo(w[j].w); a7 += bfhi(w[j].w);
        }
        s = sn;
    }
    // merge subgroup partials (butterfly over lane bit 4)
    a0 += __shfl_xor(a0, 16); a1 += __shfl_xor(a1, 16);
    a2 += __shfl_xor(a2, 16); a3 += __shfl_xor(a3, 16);
    a4 += __shfl_xor(a4, 16); a5 += __shfl_xor(a5, 16);
    a6 += __shfl_xor(a6, 16); a7 += __shfl_xor(a7, 16);

    uint4 o = make_uint4(0u, 0u, 0u, 0u);
    if (live) {
        o.x = (u32)f2bf(a0 * dd) | ((u32)f2bf(a1 * dd) << 16);
        o.y = (u32)f2bf(a2 * dd) | ((u32)f2bf(a3 * dd) << 16);
        o.z = (u32)f2bf(a4 * dd) | ((u32)f2bf(a5 * dd) << 16);
        o.w = (u32)f2bf(a6 * dd) | ((u32)f2bf(a7 * dd) << 16);
    }
    if (h0) *(uint4*)&ytile[nl][l * 8] = o;
    __syncthreads();

    // ---- MFMA phase: rows 0..15 (shared), wave w covers cols 16w..16w+15 ---
    int quad = lane >> 4, mn = l;  // quad 0..3
    bf16x8 af[4];  // A[m=mn][k = kk*32 + quad*8 + j]
#pragma unroll
    for (int kk = 0; kk < 4; ++kk)
        af[kk] = *reinterpret_cast<const bf16x8*>(&ytile[mn][kk * 32 + quad * 8]);

    int col = wave * 16 + mn;
    f32x4 acc = {0.f, 0.f, 0.f, 0.f};
#pragma unroll
    for (int kk = 0; kk < 4; ++kk) {
        bf16x8 bf =
            *reinterpret_cast<const bf16x8*>(&WfT[col * 128 + kk * 32 + quad * 8]);
        acc = __builtin_amdgcn_mfma_f32_16x16x32_bf16(af[kk], bf, acc, 0, 0, 0);
    }
    float bc = bb[col];
#pragma unroll
    for (int r = 0; r < 4; ++r) {  // C/D: col=lane&15, row=quad*4+r
        int row = quad * 4 + r;
        int gn = blk * 16 + row;
        if (gn < N)
            __builtin_nontemporal_store(f2bf((acc[r] + bc) * disS[row]),
                                        ts + (long)gn * 128 + col);
    }
}

// ---------------- gather2 + bcat + reparam ----------------------------------
// val = dd*(ts[d] + sum_s ts[s]) + bcat ; cols 0..63 mu, 64..127 ls.
// Same dual-subgroup decomposition: 2 nodes/wave, 2 subgroups/node.
__global__ __launch_bounds__(256) void gather2(const u32* __restrict__ ts,
                                               const int* __restrict__ csr,
                                               const u32* __restrict__ rowstart,
                                               const float* __restrict__ dis,
                                               const float* __restrict__ bcat,
                                               const float* __restrict__ eps,
                                               float* __restrict__ out, int N) {
    int tid = threadIdx.x;
    int gw = (blockIdx.x * 256 + tid) >> 6;  // global wave id
    int lane = tid & 63;
    int nsub = lane >> 5, h = (lane >> 4) & 1, l = lane & 15;
    int node = gw * 2 + nsub;
    bool live = node < N;
    int nodeC = live ? node : 0;
    float dd = dis[nodeC];
    u32 beg = live ? rowstart[nodeC] : 0u;
    u32 end = live ? rowstart[nodeC + 1] : 0u;
    u32 cut = beg + ((end - beg + 1u) >> 1);
    u32 mybeg = h ? cut : beg;
    u32 myend = h ? end : cut;
    const uint4* ts4 = (const uint4*)ts;

    uint4 selfv = ts4[(long)nodeC * 16 + l];
    bool h0 = (h == 0);
    float a0 = h0 ? bflo(selfv.x) : 0.f, a1 = h0 ? bfhi(selfv.x) : 0.f;
    float a2 = h0 ? bflo(selfv.y) : 0.f, a3 = h0 ? bfhi(selfv.y) : 0.f;
    float a4 = h0 ? bflo(selfv.z) : 0.f, a5 = h0 ? bfhi(selfv.z) : 0.f;
    float a6 = h0 ? bflo(selfv.w) : 0.f, a7 = h0 ? bfhi(selfv.w) : 0.f;

    int sbase = nsub * 32 + h * 16;
    int s = (l < 8 && mybeg + (u32)l < myend) ? csr[mybeg + l] : N;
    for (u32 e0 = mybeg; e0 < myend; e0 += 8) {
        u32 e1 = e0 + 8;
        int sn = (l < 8 && e1 < myend && e1 + (u32)l < myend) ? csr[e1 + l] : N;
        uint4 w[8];
#pragma unroll
        for (int j = 0; j < 8; ++j) {
            int sj = __shfl(s, sbase + j);
            w[j] = ts4[(long)sj * 16 + l];
        }
#pragma unroll
        for (int j = 0; j < 8; ++j) {
            a0 += bflo(w[j].x); a1 += bfhi(w[j].x);
            a2 += bflo(w[j].y); a3 += bfhi(w[j].y);
            a4 += bflo(w[j].z); a5 += bfhi(w[j].z);
            a6 += bflo(w[j].w); a7 += bfhi(w[j].w);
        }
        s = sn;
    }
    // merge subgroup partials
    a0 += __shfl_xor(a0, 16); a1 += __shfl_xor(a1, 16);
    a2 += __shfl_xor(a2, 16); a3 += __shfl_xor(a3, 16);
    a4 += __shfl_xor(a4, 16); a5 += __shfl_xor(a5, 16);
    a6 += __shfl_xor(a6, 16); a7 += __shfl_xor(a7, 16);

    int c0 = l * 8;  // cols c0..c0+7 (l<8: mu cols c0; l>=8: ls cols c0-64)
    f32x4 clo = ((const f32x4*)bcat)[2 * l], chi = ((const f32x4*)bcat)[2 * l + 1];
    float v0 = a0 * dd + clo[0];
    float v1 = a1 * dd + clo[1];
    float v2 = a2 * dd + clo[2];
    float v3 = a3 * dd + clo[3];
    float v4 = a4 * dd + chi[0];
    float v5 = a5 * dd + chi[1];
    float v6 = a6 * dd + chi[2];
    float v7 = a7 * dd + chi[3];

    // ls values live 8 lanes up within the same subgroup.
    int srcl = lane + 8;
    float w0 = __shfl(v0, srcl), w1 = __shfl(v1, srcl), w2 = __shfl(v2, srcl),
          w3 = __shfl(v3, srcl), w4 = __shfl(v4, srcl), w5 = __shfl(v5, srcl),
          w6 = __shfl(v6, srcl), w7 = __shfl(v7, srcl);

    if (!live || h != 0) return;  // subgroup 0 holds full sums; it stores
    long NO = (long)N * 64;
    if (l < 8) {  // mu cols c0..c0+7 ; also compute z
        float* mu = out + NO + (long)node * 64 + c0;
        __builtin_nontemporal_store(f32x4{v0, v1, v2, v3}, (f32x4*)mu);
        __builtin_nontemporal_store(f32x4{v4, v5, v6, v7}, (f32x4*)mu + 1);
        const f32x4* ep = (const f32x4*)(eps + (long)node * 64 + c0);
        f32x4 e0v = __builtin_nontemporal_load(ep);
        f32x4 e1v = __builtin_nontemporal_load(ep + 1);
        float* z = out + (long)node * 64 + c0;
        f32x4 z0 = {v0 + e0v[0] * __expf(w0), v1 + e0v[1] * __expf(w1),
                    v2 + e0v[2] * __expf(w2), v3 + e0v[3] * __expf(w3)};
        f32x4 z1 = {v4 + e1v[0] * __expf(w4), v5 + e1v[1] * __expf(w5),
                    v6 + e1v[2] * __expf(w6), v7 + e1v[3] * __expf(w7)};
        __builtin_nontemporal_store(z0, (f32x4*)z);
        __builtin_nontemporal_store(z1, (f32x4*)z + 1);
    } else {      // logstd cols (c0-64)..(c0-64+7)
        float* ls = out + 2 * NO + (long)node * 64 + (c0 - 64);
        __builtin_nontemporal_store(f32x4{v0, v1, v2, v3}, (f32x4*)ls);
        __builtin_nontemporal_store(f32x4{v4, v5, v6, v7}, (f32x4*)ls + 1);
    }
}

// ---------------------------------------------------------------------------
extern "C" void kernel_launch(void* const* d_in, const int* in_sizes, int n_in,
                              void* d_out, int out_size, void* d_ws, size_t ws_size,
                              hipStream_t stream) {
    const float* x   = (const float*)d_in[0];
    const int* ei    = (const int*)d_in[1];
    const float* W1  = (const float*)d_in[2];
    const float* b1  = (const float*)d_in[3];
    const float* Wmu = (const float*)d_in[4];
    const float* bmu = (const float*)d_in[5];
    const float* Wls = (const float*)d_in[6];
    const float* bls = (const float*)d_in[7];
    const float* eps = (const float*)d_in[8];
    float* out = (float*)d_out;

    const int N = in_sizes[0] / 128;   // 100000
    const int E = in_sizes[1] / 2;     // 1600000
    const int* src = ei;
    const int* dst = ei + E;
    const int NB = (N + 255) / 256;    // 391

    // WS layout (bytes), total ~60.4 MB.
    char* ws = (char*)d_ws;
    u32* deg       = (u32*)(ws + 0);         //   400,000
    u32* rowstart  = (u32*)(ws + 401408);    //   400,004
    u32* blockSums = (u32*)(ws + 802816);    //     2,048
    u32* blockOffs = (u32*)(ws + 804864);    //     2,048
    float* dis     = (float*)(ws + 806912);  //   400,000
    u16* WfT       = (u16*)(ws + 1208320);   //    32,768 (bf16, transposed)
    float* bb      = (float*)(ws + 1241088); //       512
    float* bcat    = (float*)(ws + 1241600); //       512
    u8* loc        = (u8*)(ws + 1242112);    // 1,600,000
    int* csr       = (int*)(ws + 2842112);   // 6,400,000
    u32* xs        = (u32*)(ws + 9242112);   // 25,600,256 ((N+1) rows bf16)
    u32* ts        = (u32*)(ws + 34842368);  // 25,600,256 ((N+1) rows bf16)

    hipMemsetAsync(deg, 0, 400000, stream);

    int gridE4 = (E / 4 + 255) / 256;
    deg_hist<<<gridE4, 256, 0, stream>>>(dst, deg, loc, E);
    scanA<<<NB, 256, 0, stream>>>(deg, blockSums, N);
    scanB<<<1, 512, 0, stream>>>(blockSums, blockOffs, NB);
    scanC<<<NB, 256, 0, stream>>>(deg, blockOffs, rowstart, dis, N, E);
    place_kernel<<<gridE4, 256, 0, stream>>>(src, dst, loc, rowstart, csr, E);
    fuse_w<<<64, 256, 0, stream>>>(W1, Wmu, Wls, b1, bmu, bls, WfT, bb, bcat);

    long Qc = (long)(N + 1) * 32;  // uint2-granular threads incl. zero row
    convert_x<<<(int)((Qc + 255) / 256), 256, 0, stream>>>(x, dis, xs, ts, N);

    int gridT = (N + 15) / 16;                    // 16 nodes / 512-thread block
    g1gemm<<<gridT, 512, 0, stream>>>(xs, csr, rowstart, dis, WfT, bb,
                                      (u16*)ts, N);

    int gridG = (((N + 1) / 2 + 3) / 4);          // 4 waves/block, 2 nodes/wave
    gather2<<<gridG, 256, 0, stream>>>(ts, csr, rowstart, dis, bcat, eps, out, N);
}